// Round 13
// baseline (165.908 us; speedup 1.0000x reference)
//
#include <hip/hip_runtime.h>
#include <math.h>

#define BB 8
#define NN 2048
#define IN_DIM 256
#define OUT_DIM 128
#define M_TOT (BB*NN)          // 16384
#define CHUNK 32
#define NCHUNK (NN/CHUNK)      // 64
#define LDP 264                // padded rank-chunk stride (floats)
#define NBUCKET (BB*NCHUNK)    // 512

// ---------------- workspace layout (in floats) ----------------
static const size_t OFF_H    = 0;                                   // h: M_TOT*128
static const size_t OFF_SRC  = OFF_H   + (size_t)M_TOT*OUT_DIM;
static const size_t OFF_DST  = OFF_SRC + M_TOT;
static const size_t OFF_SD   = OFF_DST + M_TOT;                     // sorted_d
static const size_t OFF_SI   = OFF_SD  + M_TOT;                     // sorted_idx (int)
static const size_t OFF_WP   = OFF_SI  + M_TOT;                     // wpos (sorted order)
static const size_t OFF_WN   = OFF_WP  + M_TOT;                     // wneg
static const size_t OFF_CP   = OFF_WN  + M_TOT;                     // chunk sums
static const size_t OFF_CN   = OFF_CP  + (size_t)NBUCKET*OUT_DIM;
static const size_t OFF_CPW  = OFF_CN  + (size_t)NBUCKET*OUT_DIM;
static const size_t OFF_CNW  = OFF_CPW + NBUCKET;
static const size_t OFF_LO   = OFF_CNW + NBUCKET;                   // lo per query (int)
static const size_t OFF_BCNT = OFF_LO  + M_TOT;                     // bucket counts (int)
static const size_t OFF_BLST = OFF_BCNT + NBUCKET;                  // bucket lists (int)

// ---------------- Kernel A: h = x @ W^T, plus src/dst dots ----------------
// BM=32, 256 thr, R2C8, grid 512 (2 blk/CU, 8 waves/CU — proven occupancy).
// NEW: W streamed from L1/L2 via per-quad float4 along k (no W LDS at all);
// x stays in LDS transposed tile (b64 broadcast reads). LDS-unit load drops
// 30cy/k/wave -> ~6cy/k/wave; kernel becomes VALU/issue-bound (~10 us model).
__global__ __launch_bounds__(256, 2) void gat_gemm_kernel(
    const float* __restrict__ x, const float* __restrict__ W,
    const float* __restrict__ a_src, const float* __restrict__ a_dst,
    float* __restrict__ h, float* __restrict__ src, float* __restrict__ dstv)
{
    __shared__ float xs[32][34];     // [k][m], 34 pad (8B-aligned rows)
    __shared__ float redS[32][16];
    __shared__ float redD[32][16];
    const int tid = threadIdx.x;
    const int m0 = blockIdx.x * 32;
    const int mt = tid >> 4;   // 0..15 -> rows mt*2, mt*2+1
    const int ot = tid & 15;   // 0..15 -> cols ot*4..+3 and 64+ot*4..+3
    float acc[2][8];
#pragma unroll
    for (int i = 0; i < 2; ++i)
#pragma unroll
        for (int j = 0; j < 8; ++j) acc[i][j] = 0.f;

    const float4* x4 = (const float4*)x;
    const float4* W4 = (const float4*)W;
    // W row bases in float4 units (W row = IN_DIM/4 = 64 float4)
    int wb[8];
#pragma unroll
    for (int j = 0; j < 4; ++j) {
        wb[j]     = (ot * 4 + j) * (IN_DIM / 4);
        wb[4 + j] = (64 + ot * 4 + j) * (IN_DIM / 4);
    }

    for (int k0 = 0; k0 < IN_DIM; k0 += 32) {
        {   // x tile: 32 rows x 32 k, transposed into xs[k][m]; 1 float4/thread
            int row = tid >> 3, c4 = tid & 7;
            float4 v = x4[(size_t)(m0 + row) * (IN_DIM / 4) + (k0 >> 2) + c4];
            xs[c4 * 4 + 0][row] = v.x; xs[c4 * 4 + 1][row] = v.y;
            xs[c4 * 4 + 2][row] = v.z; xs[c4 * 4 + 3][row] = v.w;
        }
        __syncthreads();
#pragma unroll
        for (int kq = 0; kq < 8; ++kq) {
            // stream W: 8 x float4 = W[o][k0+kq*4 .. +3] for this thread's 8 o's
            float4 wr[8];
#pragma unroll
            for (int j = 0; j < 8; ++j)
                wr[j] = W4[wb[j] + (k0 >> 2) + kq];
#define DOKK(KK, COMP)                                                   \
            {                                                            \
                float xv0 = xs[kq * 4 + KK][mt * 2];                     \
                float xv1 = xs[kq * 4 + KK][mt * 2 + 1];                 \
                _Pragma("unroll")                                        \
                for (int j = 0; j < 8; ++j) {                            \
                    acc[0][j] = fmaf(xv0, wr[j].COMP, acc[0][j]);        \
                    acc[1][j] = fmaf(xv1, wr[j].COMP, acc[1][j]);        \
                }                                                        \
            }
            DOKK(0, x) DOKK(1, y) DOKK(2, z) DOKK(3, w)
#undef DOKK
        }
        __syncthreads();
    }

    // epilogue: store h tile + partial src/dst dots (identical chain to R7)
    float as8[8], ad8[8];
#pragma unroll
    for (int j = 0; j < 4; ++j) {
        as8[j]     = a_src[ot * 4 + j];      ad8[j]     = a_dst[ot * 4 + j];
        as8[4 + j] = a_src[64 + ot * 4 + j]; ad8[4 + j] = a_dst[64 + ot * 4 + j];
    }
#pragma unroll
    for (int i = 0; i < 2; ++i) {
        int m = m0 + mt * 2 + i;
        float4 v0 = {acc[i][0], acc[i][1], acc[i][2], acc[i][3]};
        float4 v1 = {acc[i][4], acc[i][5], acc[i][6], acc[i][7]};
        ((float4*)h)[(size_t)m * (OUT_DIM / 4) + ot] = v0;
        ((float4*)h)[(size_t)m * (OUT_DIM / 4) + 16 + ot] = v1;
        float ps = 0.f, pd = 0.f;
#pragma unroll
        for (int j = 0; j < 8; ++j) {
            ps = fmaf(acc[i][j], as8[j], ps);
            pd = fmaf(acc[i][j], ad8[j], pd);
        }
        redS[mt * 2 + i][ot] = ps;
        redD[mt * 2 + i][ot] = pd;
    }
    __syncthreads();
    if (tid < 32) {
        float ss = 0.f, dd = 0.f;
#pragma unroll
        for (int t = 0; t < 16; ++t) { ss += redS[tid][t]; dd += redD[tid][t]; }
        src[m0 + tid] = ss;
        dstv[m0 + tid] = dd;
    }
}

// ---------------- Kernel R: fused rank + scatter + weights (+bucket zero) ----------------
__global__ __launch_bounds__(256) void rank_kernel(
    const float* __restrict__ dstv, const int* __restrict__ mask,
    float* __restrict__ sorted_d, int* __restrict__ sorted_idx,
    float* __restrict__ wpos, float* __restrict__ wneg,
    int* __restrict__ bucketCnt)
{
    __shared__ float ld[8 * LDP];
    __shared__ int   red[32][8];
    const int tid = threadIdx.x;
    const int b  = blockIdx.x >> 6;
    const int jg = blockIdx.x & 63;
    if (tid == 0) bucketCnt[blockIdx.x] = 0;
    for (int i = tid; i < NN; i += 256)
        ld[(i >> 8) * LDP + (i & 255)] = dstv[b * NN + i];
    __syncthreads();
    const int js = tid >> 3;
    const int qq = tid & 7;
    const int jloc = jg * 32 + js;
    float myd = ld[(jloc >> 8) * LDP + (jloc & 255)];
    const float4* l4 = (const float4*)&ld[qq * LDP];
    int rank = 0;
#pragma unroll 8
    for (int t = 0; t < 64; ++t) {
        float4 v = l4[t];
        int jj = qq * 256 + t * 4;
        rank += (v.x < myd) || (v.x == myd && jj + 0 < jloc);
        rank += (v.y < myd) || (v.y == myd && jj + 1 < jloc);
        rank += (v.z < myd) || (v.z == myd && jj + 2 < jloc);
        rank += (v.w < myd) || (v.w == myd && jj + 3 < jloc);
    }
    red[js][qq] = rank;
    __syncthreads();
    if (tid < 32) {
        int j = jg * 32 + tid;
        const int* rr = red[tid];
        int rk = rr[0] + rr[1] + rr[2] + rr[3] + rr[4] + rr[5] + rr[6] + rr[7];
        float d = ld[(j >> 8) * LDP + (j & 255)];
        int mk = mask[b * NN + j];
        sorted_d[b * NN + rk] = d;
        sorted_idx[b * NN + rk] = j;
        wpos[b * NN + rk] = mk ? expf(d) : 0.f;
        wneg[b * NN + rk] = mk ? expf(0.2f * d) : 0.f;
    }
}

// ---------------- Kernel D1: chunk sums + query search/bucketing ----------------
__global__ __launch_bounds__(256) void chunksum_kernel(
    const float* __restrict__ h, const int* __restrict__ sidx,
    const float* __restrict__ wpos, const float* __restrict__ wneg,
    const float* __restrict__ sorted_d, const float* __restrict__ src,
    float* __restrict__ cPos, float* __restrict__ cNeg,
    float* __restrict__ cPosW, float* __restrict__ cNegW,
    int* __restrict__ lo_arr, int* __restrict__ bucketCnt, int* __restrict__ bucketList)
{
    __shared__ float sd_s[NN];     // 8 KB
    const int tid = threadIdx.x;
    const int b = blockIdx.x >> 6;
    const int c = blockIdx.x & 63;
    const int r0 = c * CHUNK;
    const float4* sd4 = (const float4*)(sorted_d + b * NN);
    {
        float4 v0 = sd4[tid];
        *(float4*)&sd_s[tid * 4] = v0;
        float4 v1 = sd4[256 + tid];
        *(float4*)&sd_s[1024 + tid * 4] = v1;
    }
    __syncthreads();
    if (tid < 128) {
        int o = tid;
        float ap = 0.f, an = 0.f, apw = 0.f, anw = 0.f;
        for (int r = 0; r < CHUNK; ++r) {
            int rr = b * NN + r0 + r;
            int jj = sidx[rr];
            float wp = wpos[rr], wn = wneg[rr];
            float hv = h[((size_t)b * NN + jj) * OUT_DIM + o];
            ap = fmaf(wp, hv, ap);
            an = fmaf(wn, hv, an);
            apw += wp; anw += wn;
        }
        int cidx = blockIdx.x;
        cPos[(size_t)cidx * OUT_DIM + o] = ap;
        cNeg[(size_t)cidx * OUT_DIM + o] = an;
        if (o == 0) { cPosW[cidx] = apw; cNegW[cidx] = anw; }
    } else if (tid < 160) {
        int ql = r0 + (tid - 128);
        int q = b * NN + ql;
        float t = -src[q];
        int lo = 0, hi = NN;
        while (lo < hi) {
            int mid = (lo + hi) >> 1;
            if (sd_s[mid] > t) hi = mid; else lo = mid + 1;
        }
        lo_arr[q] = lo;
        int cq = lo >> 5; if (cq > NCHUNK - 1) cq = NCHUNK - 1;
        int bidx = b * NCHUNK + cq;
        int pos = atomicAdd(&bucketCnt[bidx], 1);
        bucketList[(size_t)bidx * NN + pos] = q;
    }
}

// ---------------- Kernel E: fused expand + query (per split-chunk bucket) ----------------
__global__ __launch_bounds__(256, 2) void fusedout_kernel(
    const float* __restrict__ h, const int* __restrict__ sidx,
    const float* __restrict__ wpos, const float* __restrict__ wneg,
    const float* __restrict__ cPos, const float* __restrict__ cNeg,
    const float* __restrict__ cPosW, const float* __restrict__ cNegW,
    const float* __restrict__ src, const int* __restrict__ lo_arr,
    const int* __restrict__ bucketCnt, const int* __restrict__ bucketList,
    float* __restrict__ out)
{
    __shared__ float hs[CHUNK][OUT_DIM];
    __shared__ float PreL[CHUNK + 1][OUT_DIM];
    __shared__ float SufL[CHUNK + 1][OUT_DIM];
    __shared__ float wn_s[CHUNK], wp_s[CHUNK];
    __shared__ int   si_s[CHUNK];
    __shared__ float prewL[CHUNK + 1], sufwL[CHUNK + 1];
    const int tid = threadIdx.x;
    const int b = blockIdx.x >> 6;
    const int c = blockIdx.x & 63;
    const int r0 = c * CHUNK;
    const size_t hb = (size_t)b * NN;

    if (tid < CHUNK) {
        int rr = b * NN + r0 + tid;
        si_s[tid] = sidx[rr];
        wn_s[tid] = wneg[rr];
        wp_s[tid] = wpos[rr];
    }
    __syncthreads();
#pragma unroll
    for (int it = 0; it < 4; ++it) {
        int row = it * 8 + (tid >> 5);
        int c4 = tid & 31;
        float4 v = ((const float4*)h)[(hb + si_s[row]) * (OUT_DIM / 4) + c4];
        *(float4*)&hs[row][c4 * 4] = v;
    }
    float base = 0.f;
    if (tid < 128) {
        for (int cc = 0; cc < c; ++cc)
            base += cNeg[(size_t)(b * NCHUNK + cc) * OUT_DIM + tid];
    } else {
        int o = tid - 128;
        for (int cc = c + 1; cc < NCHUNK; ++cc)
            base += cPos[(size_t)(b * NCHUNK + cc) * OUT_DIM + o];
    }
    __syncthreads();
    if (tid < 128) {
        int o = tid;
        float acc = base;
#pragma unroll
        for (int r = 0; r < CHUNK; ++r) {
            PreL[r][o] = acc;
            acc = fmaf(wn_s[r], hs[r][o], acc);
        }
        PreL[CHUNK][o] = acc;
    } else {
        int o = tid - 128;
        float acc = base;
        SufL[CHUNK][o] = acc;
#pragma unroll
        for (int r = CHUNK - 1; r >= 0; --r) {
            acc = fmaf(wp_s[r], hs[r][o], acc);
            SufL[r][o] = acc;
        }
    }
    if (tid == 0) {
        float a = 0.f;
        for (int cc = 0; cc < c; ++cc) a += cNegW[b * NCHUNK + cc];
        for (int r = 0; r < CHUNK; ++r) { prewL[r] = a; a += wn_s[r]; }
        prewL[CHUNK] = a;
    }
    if (tid == 128) {
        float a = 0.f;
        for (int cc = c + 1; cc < NCHUNK; ++cc) a += cPosW[b * NCHUNK + cc];
        sufwL[CHUNK] = a;
        for (int r = CHUNK - 1; r >= 0; --r) { a += wp_s[r]; sufwL[r] = a; }
    }
    __syncthreads();

    const int bidx = blockIdx.x;
    const int cnt = bucketCnt[bidx];
    const int o  = tid & 127;
    const int qh = tid >> 7;
    for (int i = qh; i < cnt; i += 2) {
        int q = bucketList[(size_t)bidx * NN + i];
        int rl = lo_arr[q] - r0;               // 0..32
        float sv = src[q];
        float pe = expf(sv), pn = expf(0.2f * sv);
        float den = pe * sufwL[rl] + pn * prewL[rl];
        float sc = (den > 0.f) ? 1.f / den : 0.f;
        float num = pe * SufL[rl][o] + pn * PreL[rl][o];
        out[(size_t)q * OUT_DIM + o] = num * sc;
    }
}

// ---------------- launcher ----------------
extern "C" void kernel_launch(void* const* d_in, const int* in_sizes, int n_in,
                              void* d_out, int out_size, void* d_ws, size_t ws_size,
                              hipStream_t stream)
{
    const float* x     = (const float*)d_in[0];
    const int*   mask  = (const int*)d_in[1];
    const float* W     = (const float*)d_in[2];
    const float* a_src = (const float*)d_in[3];
    const float* a_dst = (const float*)d_in[4];
    float* out = (float*)d_out;
    float* ws  = (float*)d_ws;

    float* h        = ws + OFF_H;
    float* src      = ws + OFF_SRC;
    float* dstv     = ws + OFF_DST;
    float* sorted_d = ws + OFF_SD;
    int*   sidx     = (int*)(ws + OFF_SI);
    float* wpos     = ws + OFF_WP;
    float* wneg     = ws + OFF_WN;
    float* cPos     = ws + OFF_CP;
    float* cNeg     = ws + OFF_CN;
    float* cPosW    = ws + OFF_CPW;
    float* cNegW    = ws + OFF_CNW;
    int*   lo_arr   = (int*)(ws + OFF_LO);
    int*   bucketCnt= (int*)(ws + OFF_BCNT);
    int*   bucketList=(int*)(ws + OFF_BLST);

    gat_gemm_kernel<<<M_TOT / 32, 256, 0, stream>>>(x, W, a_src, a_dst, h, src, dstv);
    rank_kernel<<<NBUCKET, 256, 0, stream>>>(dstv, mask, sorted_d, sidx, wpos, wneg, bucketCnt);
    chunksum_kernel<<<NBUCKET, 256, 0, stream>>>(h, sidx, wpos, wneg, sorted_d, src,
                                                 cPos, cNeg, cPosW, cNegW,
                                                 lo_arr, bucketCnt, bucketList);
    fusedout_kernel<<<NBUCKET, 256, 0, stream>>>(h, sidx, wpos, wneg, cPos, cNeg, cPosW, cNegW,
                                                 src, lo_arr, bucketCnt, bucketList, out);
}

// Round 14
// 64.539 us; speedup vs baseline: 2.5707x; 2.5707x over previous
//
#include <hip/hip_runtime.h>
#include <math.h>

#define BB 8
#define NN 2048
#define IN_DIM 256
#define OUT_DIM 128
#define M_TOT (BB*NN)          // 16384
#define CHUNK 32
#define NCHUNK (NN/CHUNK)      // 64
#define LDP 264                // padded rank-chunk stride (floats)
#define NBUCKET (BB*NCHUNK)    // 512

typedef __attribute__((ext_vector_type(8))) short bf16x8;
typedef __attribute__((ext_vector_type(16))) float f32x16;

__device__ inline ushort f2bf(float f) {
    unsigned u = __float_as_uint(f);
    unsigned r = (u + 0x7FFFu + ((u >> 16) & 1u)) >> 16;   // RNE
    return (ushort)r;
}
__device__ inline float bf2f(ushort b) { return __uint_as_float(((unsigned)b) << 16); }

// ---------------- workspace layout (in floats) ----------------
static const size_t OFF_H    = 0;                                   // h: M_TOT*128
static const size_t OFF_SRC  = OFF_H   + (size_t)M_TOT*OUT_DIM;
static const size_t OFF_DST  = OFF_SRC + M_TOT;
static const size_t OFF_SD   = OFF_DST + M_TOT;                     // sorted_d
static const size_t OFF_SI   = OFF_SD  + M_TOT;                     // sorted_idx (int)
static const size_t OFF_WP   = OFF_SI  + M_TOT;                     // wpos (sorted order)
static const size_t OFF_WN   = OFF_WP  + M_TOT;                     // wneg
static const size_t OFF_CP   = OFF_WN  + M_TOT;                     // chunk sums
static const size_t OFF_CN   = OFF_CP  + (size_t)NBUCKET*OUT_DIM;
static const size_t OFF_CPW  = OFF_CN  + (size_t)NBUCKET*OUT_DIM;
static const size_t OFF_CNW  = OFF_CPW + NBUCKET;
static const size_t OFF_LO   = OFF_CNW + NBUCKET;                   // lo per query (int)
static const size_t OFF_BCNT = OFF_LO  + M_TOT;                     // bucket counts (int)
static const size_t OFF_BLST = OFF_BCNT + NBUCKET;                  // bucket lists (int)

// ---------------- Kernel A: MFMA bf16x2-split GEMM + src/dst dots ----------------
// h = x @ W^T via 3x mfma_f32_32x32x16_bf16 (hi*hi + hi*lo + lo*hi).
// Grid 256 (1 blk/CU), 256 thr = 4 waves: wave = 32 rows x 64 cols.
// K-tile 64; x and W converted f32->bf16(hi,lo) during LDS staging.
__global__ __launch_bounds__(256) void gat_gemm_kernel(
    const float* __restrict__ x, const float* __restrict__ W,
    const float* __restrict__ a_src, const float* __restrict__ a_dst,
    float* __restrict__ h, float* __restrict__ src, float* __restrict__ dstv)
{
    __shared__ ushort xh[64][72], xl[64][72];     // 9216 B each
    __shared__ ushort wh[128][72], wl[128][72];   // 18432 B each
    __shared__ float  redS[64][2], redD[64][2];
    const int tid  = threadIdx.x;
    const int lane = tid & 63;
    const int wv   = tid >> 6;            // 0..3
    const int m0   = blockIdx.x * 64;
    const int mrow = (wv >> 1) * 32;      // 0 / 32
    const int nbase = (wv & 1) * 64;      // 0 / 64
    const int l31  = lane & 31;
    const int lg   = lane >> 5;           // k-chunk group 0/1

    f32x16 acc0, acc1;
#pragma unroll
    for (int i = 0; i < 16; ++i) { acc0[i] = 0.f; acc1[i] = 0.f; }

    const float4* x4 = (const float4*)x;
    const float4* W4 = (const float4*)W;
    const int xrow = tid >> 2, xseg = tid & 3;   // x: 64 rows x 4 segs of 16

    for (int kt = 0; kt < 4; ++kt) {
        const int k0 = kt * 64;
        {   // stage x: 16 f32/thread, convert to hi/lo bf16
            size_t base = (size_t)(m0 + xrow) * (IN_DIM / 4) + (k0 >> 2) + xseg * 4;
#pragma unroll
            for (int s = 0; s < 4; ++s) {
                float4 v = x4[base + s];
                int kk = xseg * 16 + s * 4;
                ushort h0 = f2bf(v.x), h1 = f2bf(v.y), h2 = f2bf(v.z), h3 = f2bf(v.w);
                xh[xrow][kk + 0] = h0; xh[xrow][kk + 1] = h1;
                xh[xrow][kk + 2] = h2; xh[xrow][kk + 3] = h3;
                xl[xrow][kk + 0] = f2bf(v.x - bf2f(h0));
                xl[xrow][kk + 1] = f2bf(v.y - bf2f(h1));
                xl[xrow][kk + 2] = f2bf(v.z - bf2f(h2));
                xl[xrow][kk + 3] = f2bf(v.w - bf2f(h3));
            }
        }
#pragma unroll
        for (int it = 0; it < 2; ++it) {   // stage W: 32 f32/thread
            int idx = tid + it * 256;
            int wrow = idx >> 2, wseg = idx & 3;
            size_t base = (size_t)wrow * (IN_DIM / 4) + (k0 >> 2) + wseg * 4;
#pragma unroll
            for (int s = 0; s < 4; ++s) {
                float4 v = W4[base + s];
                int kk = wseg * 16 + s * 4;
                ushort h0 = f2bf(v.x), h1 = f2bf(v.y), h2 = f2bf(v.z), h3 = f2bf(v.w);
                wh[wrow][kk + 0] = h0; wh[wrow][kk + 1] = h1;
                wh[wrow][kk + 2] = h2; wh[wrow][kk + 3] = h3;
                wl[wrow][kk + 0] = f2bf(v.x - bf2f(h0));
                wl[wrow][kk + 1] = f2bf(v.y - bf2f(h1));
                wl[wrow][kk + 2] = f2bf(v.z - bf2f(h2));
                wl[wrow][kk + 3] = f2bf(v.w - bf2f(h3));
            }
        }
        __syncthreads();
#pragma unroll
        for (int ks = 0; ks < 4; ++ks) {
            int ko = ks * 16 + lg * 8;
            bf16x8 aH  = *(const bf16x8*)&xh[mrow + l31][ko];
            bf16x8 aL  = *(const bf16x8*)&xl[mrow + l31][ko];
            bf16x8 b0H = *(const bf16x8*)&wh[nbase + l31][ko];
            bf16x8 b0L = *(const bf16x8*)&wl[nbase + l31][ko];
            bf16x8 b1H = *(const bf16x8*)&wh[nbase + 32 + l31][ko];
            bf16x8 b1L = *(const bf16x8*)&wl[nbase + 32 + l31][ko];
            acc0 = __builtin_amdgcn_mfma_f32_32x32x16_bf16(aH, b0H, acc0, 0, 0, 0);
            acc0 = __builtin_amdgcn_mfma_f32_32x32x16_bf16(aH, b0L, acc0, 0, 0, 0);
            acc0 = __builtin_amdgcn_mfma_f32_32x32x16_bf16(aL, b0H, acc0, 0, 0, 0);
            acc1 = __builtin_amdgcn_mfma_f32_32x32x16_bf16(aH, b1H, acc1, 0, 0, 0);
            acc1 = __builtin_amdgcn_mfma_f32_32x32x16_bf16(aH, b1L, acc1, 0, 0, 0);
            acc1 = __builtin_amdgcn_mfma_f32_32x32x16_bf16(aL, b1H, acc1, 0, 0, 0);
        }
        __syncthreads();
    }

    // epilogue: write h + fused src/dst dots
    float asv0 = a_src[nbase + l31], asv1 = a_src[nbase + 32 + l31];
    float adv0 = a_dst[nbase + l31], adv1 = a_dst[nbase + 32 + l31];
#pragma unroll
    for (int r = 0; r < 16; ++r) {
        int row = (r & 3) + 8 * (r >> 2) + 4 * lg;
        size_t off = (size_t)(m0 + mrow + row) * OUT_DIM + nbase;
        h[off + l31] = acc0[r];
        h[off + 32 + l31] = acc1[r];
        float ps = acc0[r] * asv0 + acc1[r] * asv1;
        float pd = acc0[r] * adv0 + acc1[r] * adv1;
#pragma unroll
        for (int s = 1; s < 32; s <<= 1) {
            ps += __shfl_xor(ps, s, 32);
            pd += __shfl_xor(pd, s, 32);
        }
        if (l31 == 0) {
            redS[mrow + row][wv & 1] = ps;
            redD[mrow + row][wv & 1] = pd;
        }
    }
    __syncthreads();
    if (tid < 64) {
        src[m0 + tid]  = redS[tid][0] + redS[tid][1];
        dstv[m0 + tid] = redD[tid][0] + redD[tid][1];
    }
}

// ---------------- Kernel R: fused rank + scatter + weights (+bucket zero) ----------------
__global__ __launch_bounds__(256) void rank_kernel(
    const float* __restrict__ dstv, const int* __restrict__ mask,
    float* __restrict__ sorted_d, int* __restrict__ sorted_idx,
    float* __restrict__ wpos, float* __restrict__ wneg,
    int* __restrict__ bucketCnt)
{
    __shared__ float ld[8 * LDP];
    __shared__ int   red[32][8];
    const int tid = threadIdx.x;
    const int b  = blockIdx.x >> 6;
    const int jg = blockIdx.x & 63;
    if (tid == 0) bucketCnt[blockIdx.x] = 0;
    for (int i = tid; i < NN; i += 256)
        ld[(i >> 8) * LDP + (i & 255)] = dstv[b * NN + i];
    __syncthreads();
    const int js = tid >> 3;
    const int qq = tid & 7;
    const int jloc = jg * 32 + js;
    float myd = ld[(jloc >> 8) * LDP + (jloc & 255)];
    const float4* l4 = (const float4*)&ld[qq * LDP];
    int rank = 0;
#pragma unroll 8
    for (int t = 0; t < 64; ++t) {
        float4 v = l4[t];
        int jj = qq * 256 + t * 4;
        rank += (v.x < myd) || (v.x == myd && jj + 0 < jloc);
        rank += (v.y < myd) || (v.y == myd && jj + 1 < jloc);
        rank += (v.z < myd) || (v.z == myd && jj + 2 < jloc);
        rank += (v.w < myd) || (v.w == myd && jj + 3 < jloc);
    }
    red[js][qq] = rank;
    __syncthreads();
    if (tid < 32) {
        int j = jg * 32 + tid;
        const int* rr = red[tid];
        int rk = rr[0] + rr[1] + rr[2] + rr[3] + rr[4] + rr[5] + rr[6] + rr[7];
        float d = ld[(j >> 8) * LDP + (j & 255)];
        int mk = mask[b * NN + j];
        sorted_d[b * NN + rk] = d;
        sorted_idx[b * NN + rk] = j;
        wpos[b * NN + rk] = mk ? expf(d) : 0.f;
        wneg[b * NN + rk] = mk ? expf(0.2f * d) : 0.f;
    }
}

// ---------------- Kernel D1: chunk sums + query search/bucketing ----------------
__global__ __launch_bounds__(256) void chunksum_kernel(
    const float* __restrict__ h, const int* __restrict__ sidx,
    const float* __restrict__ wpos, const float* __restrict__ wneg,
    const float* __restrict__ sorted_d, const float* __restrict__ src,
    float* __restrict__ cPos, float* __restrict__ cNeg,
    float* __restrict__ cPosW, float* __restrict__ cNegW,
    int* __restrict__ lo_arr, int* __restrict__ bucketCnt, int* __restrict__ bucketList)
{
    __shared__ float sd_s[NN];     // 8 KB
    const int tid = threadIdx.x;
    const int b = blockIdx.x >> 6;
    const int c = blockIdx.x & 63;
    const int r0 = c * CHUNK;
    const float4* sd4 = (const float4*)(sorted_d + b * NN);
    {
        float4 v0 = sd4[tid];
        *(float4*)&sd_s[tid * 4] = v0;
        float4 v1 = sd4[256 + tid];
        *(float4*)&sd_s[1024 + tid * 4] = v1;
    }
    __syncthreads();
    if (tid < 128) {
        int o = tid;
        float ap = 0.f, an = 0.f, apw = 0.f, anw = 0.f;
        for (int r = 0; r < CHUNK; ++r) {
            int rr = b * NN + r0 + r;
            int jj = sidx[rr];
            float wp = wpos[rr], wn = wneg[rr];
            float hv = h[((size_t)b * NN + jj) * OUT_DIM + o];
            ap = fmaf(wp, hv, ap);
            an = fmaf(wn, hv, an);
            apw += wp; anw += wn;
        }
        int cidx = blockIdx.x;
        cPos[(size_t)cidx * OUT_DIM + o] = ap;
        cNeg[(size_t)cidx * OUT_DIM + o] = an;
        if (o == 0) { cPosW[cidx] = apw; cNegW[cidx] = anw; }
    } else if (tid < 160) {
        int ql = r0 + (tid - 128);
        int q = b * NN + ql;
        float t = -src[q];
        int lo = 0, hi = NN;
        while (lo < hi) {
            int mid = (lo + hi) >> 1;
            if (sd_s[mid] > t) hi = mid; else lo = mid + 1;
        }
        lo_arr[q] = lo;
        int cq = lo >> 5; if (cq > NCHUNK - 1) cq = NCHUNK - 1;
        int bidx = b * NCHUNK + cq;
        int pos = atomicAdd(&bucketCnt[bidx], 1);
        bucketList[(size_t)bidx * NN + pos] = q;
    }
}

// ---------------- Kernel E: fused expand + query (per split-chunk bucket) ----------------
__global__ __launch_bounds__(256, 2) void fusedout_kernel(
    const float* __restrict__ h, const int* __restrict__ sidx,
    const float* __restrict__ wpos, const float* __restrict__ wneg,
    const float* __restrict__ cPos, const float* __restrict__ cNeg,
    const float* __restrict__ cPosW, const float* __restrict__ cNegW,
    const float* __restrict__ src, const int* __restrict__ lo_arr,
    const int* __restrict__ bucketCnt, const int* __restrict__ bucketList,
    float* __restrict__ out)
{
    __shared__ float hs[CHUNK][OUT_DIM];
    __shared__ float PreL[CHUNK + 1][OUT_DIM];
    __shared__ float SufL[CHUNK + 1][OUT_DIM];
    __shared__ float wn_s[CHUNK], wp_s[CHUNK];
    __shared__ int   si_s[CHUNK];
    __shared__ float prewL[CHUNK + 1], sufwL[CHUNK + 1];
    const int tid = threadIdx.x;
    const int b = blockIdx.x >> 6;
    const int c = blockIdx.x & 63;
    const int r0 = c * CHUNK;
    const size_t hb = (size_t)b * NN;

    if (tid < CHUNK) {
        int rr = b * NN + r0 + tid;
        si_s[tid] = sidx[rr];
        wn_s[tid] = wneg[rr];
        wp_s[tid] = wpos[rr];
    }
    __syncthreads();
#pragma unroll
    for (int it = 0; it < 4; ++it) {
        int row = it * 8 + (tid >> 5);
        int c4 = tid & 31;
        float4 v = ((const float4*)h)[(hb + si_s[row]) * (OUT_DIM / 4) + c4];
        *(float4*)&hs[row][c4 * 4] = v;
    }
    float base = 0.f;
    if (tid < 128) {
        for (int cc = 0; cc < c; ++cc)
            base += cNeg[(size_t)(b * NCHUNK + cc) * OUT_DIM + tid];
    } else {
        int o = tid - 128;
        for (int cc = c + 1; cc < NCHUNK; ++cc)
            base += cPos[(size_t)(b * NCHUNK + cc) * OUT_DIM + o];
    }
    __syncthreads();
    if (tid < 128) {
        int o = tid;
        float acc = base;
#pragma unroll
        for (int r = 0; r < CHUNK; ++r) {
            PreL[r][o] = acc;
            acc = fmaf(wn_s[r], hs[r][o], acc);
        }
        PreL[CHUNK][o] = acc;
    } else {
        int o = tid - 128;
        float acc = base;
        SufL[CHUNK][o] = acc;
#pragma unroll
        for (int r = CHUNK - 1; r >= 0; --r) {
            acc = fmaf(wp_s[r], hs[r][o], acc);
            SufL[r][o] = acc;
        }
    }
    if (tid == 0) {
        float a = 0.f;
        for (int cc = 0; cc < c; ++cc) a += cNegW[b * NCHUNK + cc];
        for (int r = 0; r < CHUNK; ++r) { prewL[r] = a; a += wn_s[r]; }
        prewL[CHUNK] = a;
    }
    if (tid == 128) {
        float a = 0.f;
        for (int cc = c + 1; cc < NCHUNK; ++cc) a += cPosW[b * NCHUNK + cc];
        sufwL[CHUNK] = a;
        for (int r = CHUNK - 1; r >= 0; --r) { a += wp_s[r]; sufwL[r] = a; }
    }
    __syncthreads();

    const int bidx = blockIdx.x;
    const int cnt = bucketCnt[bidx];
    const int o  = tid & 127;
    const int qh = tid >> 7;
    for (int i = qh; i < cnt; i += 2) {
        int q = bucketList[(size_t)bidx * NN + i];
        int rl = lo_arr[q] - r0;               // 0..32
        float sv = src[q];
        float pe = expf(sv), pn = expf(0.2f * sv);
        float den = pe * sufwL[rl] + pn * prewL[rl];
        float sc = (den > 0.f) ? 1.f / den : 0.f;
        float num = pe * SufL[rl][o] + pn * PreL[rl][o];
        out[(size_t)q * OUT_DIM + o] = num * sc;
    }
}

// ---------------- launcher ----------------
extern "C" void kernel_launch(void* const* d_in, const int* in_sizes, int n_in,
                              void* d_out, int out_size, void* d_ws, size_t ws_size,
                              hipStream_t stream)
{
    const float* x     = (const float*)d_in[0];
    const int*   mask  = (const int*)d_in[1];
    const float* W     = (const float*)d_in[2];
    const float* a_src = (const float*)d_in[3];
    const float* a_dst = (const float*)d_in[4];
    float* out = (float*)d_out;
    float* ws  = (float*)d_ws;

    float* h        = ws + OFF_H;
    float* src      = ws + OFF_SRC;
    float* dstv     = ws + OFF_DST;
    float* sorted_d = ws + OFF_SD;
    int*   sidx     = (int*)(ws + OFF_SI);
    float* wpos     = ws + OFF_WP;
    float* wneg     = ws + OFF_WN;
    float* cPos     = ws + OFF_CP;
    float* cNeg     = ws + OFF_CN;
    float* cPosW    = ws + OFF_CPW;
    float* cNegW    = ws + OFF_CNW;
    int*   lo_arr   = (int*)(ws + OFF_LO);
    int*   bucketCnt= (int*)(ws + OFF_BCNT);
    int*   bucketList=(int*)(ws + OFF_BLST);

    gat_gemm_kernel<<<M_TOT / 64, 256, 0, stream>>>(x, W, a_src, a_dst, h, src, dstv);
    rank_kernel<<<NBUCKET, 256, 0, stream>>>(dstv, mask, sorted_d, sidx, wpos, wneg, bucketCnt);
    chunksum_kernel<<<NBUCKET, 256, 0, stream>>>(h, sidx, wpos, wneg, sorted_d, src,
                                                 cPos, cNeg, cPosW, cNegW,
                                                 lo_arr, bucketCnt, bucketList);
    fusedout_kernel<<<NBUCKET, 256, 0, stream>>>(h, sidx, wpos, wneg, cPos, cNeg, cPosW, cNegW,
                                                 src, lo_arr, bucketCnt, bucketList, out);
}

// Round 15
// 55.639 us; speedup vs baseline: 2.9819x; 1.1600x over previous
//
#include <hip/hip_runtime.h>
#include <math.h>

#define BB 8
#define NN 2048
#define IN_DIM 256
#define OUT_DIM 128
#define M_TOT (BB*NN)          // 16384
#define CHUNK 32
#define NCHUNK (NN/CHUNK)      // 64
#define LDP 264                // padded rank-chunk stride (floats)
#define NBUCKET (BB*NCHUNK)    // 512

typedef __attribute__((ext_vector_type(8))) short bf16x8;
typedef __attribute__((ext_vector_type(16))) float f32x16;

__device__ inline ushort f2bf(float f) {
    unsigned u = __float_as_uint(f);
    unsigned r = (u + 0x7FFFu + ((u >> 16) & 1u)) >> 16;   // RNE
    return (ushort)r;
}
__device__ inline float bf2f(ushort b) { return __uint_as_float(((unsigned)b) << 16); }
__device__ inline unsigned pack2(ushort a, ushort b) { return (unsigned)a | ((unsigned)b << 16); }

// ---------------- workspace layout (in floats) ----------------
static const size_t OFF_H    = 0;                                   // h: M_TOT*128
static const size_t OFF_SRC  = OFF_H   + (size_t)M_TOT*OUT_DIM;
static const size_t OFF_DST  = OFF_SRC + M_TOT;
static const size_t OFF_SD   = OFF_DST + M_TOT;                     // sorted_d
static const size_t OFF_SI   = OFF_SD  + M_TOT;                     // sorted_idx (int)
static const size_t OFF_WP   = OFF_SI  + M_TOT;                     // wpos (sorted order)
static const size_t OFF_WN   = OFF_WP  + M_TOT;                     // wneg
static const size_t OFF_CP   = OFF_WN  + M_TOT;                     // chunk sums
static const size_t OFF_CN   = OFF_CP  + (size_t)NBUCKET*OUT_DIM;
static const size_t OFF_CPW  = OFF_CN  + (size_t)NBUCKET*OUT_DIM;
static const size_t OFF_CNW  = OFF_CPW + NBUCKET;
static const size_t OFF_LO   = OFF_CNW + NBUCKET;                   // lo per query (int)
static const size_t OFF_BCNT = OFF_LO  + M_TOT;                     // bucket counts (int)
static const size_t OFF_BLST = OFF_BCNT + NBUCKET;                  // bucket lists (int)

// ---------------- Kernel A: MFMA bf16x2-split GEMM + src/dst dots ----------------
__global__ __launch_bounds__(256) void gat_gemm_kernel(
    const float* __restrict__ x, const float* __restrict__ W,
    const float* __restrict__ a_src, const float* __restrict__ a_dst,
    float* __restrict__ h, float* __restrict__ src, float* __restrict__ dstv)
{
    __shared__ ushort xh[64][72], xl[64][72];     // 9216 B each
    __shared__ ushort wh[128][72], wl[128][72];   // 18432 B each
    __shared__ float  redS[64][2], redD[64][2];
    const int tid  = threadIdx.x;
    const int lane = tid & 63;
    const int wv   = tid >> 6;            // 0..3
    const int m0   = blockIdx.x * 64;
    const int mrow = (wv >> 1) * 32;      // 0 / 32
    const int nbase = (wv & 1) * 64;      // 0 / 64
    const int l31  = lane & 31;
    const int lg   = lane >> 5;           // k-chunk group 0/1

    f32x16 acc0, acc1;
#pragma unroll
    for (int i = 0; i < 16; ++i) { acc0[i] = 0.f; acc1[i] = 0.f; }

    const float4* x4 = (const float4*)x;
    const float4* W4 = (const float4*)W;
    const int xrow = tid >> 2, xseg = tid & 3;   // x: 64 rows x 4 segs of 16

    for (int kt = 0; kt < 4; ++kt) {
        const int k0 = kt * 64;
        {   // stage x: 16 f32/thread -> hi/lo bf16, packed b64 writes
            size_t base = (size_t)(m0 + xrow) * (IN_DIM / 4) + (k0 >> 2) + xseg * 4;
#pragma unroll
            for (int s = 0; s < 4; ++s) {
                float4 v = x4[base + s];
                int kk = xseg * 16 + s * 4;
                ushort h0 = f2bf(v.x), h1 = f2bf(v.y), h2 = f2bf(v.z), h3 = f2bf(v.w);
                ushort e0 = f2bf(v.x - bf2f(h0)), e1 = f2bf(v.y - bf2f(h1));
                ushort e2 = f2bf(v.z - bf2f(h2)), e3 = f2bf(v.w - bf2f(h3));
                uint2 ph; ph.x = pack2(h0, h1); ph.y = pack2(h2, h3);
                uint2 pl; pl.x = pack2(e0, e1); pl.y = pack2(e2, e3);
                *(uint2*)&xh[xrow][kk] = ph;
                *(uint2*)&xl[xrow][kk] = pl;
            }
        }
#pragma unroll
        for (int it = 0; it < 2; ++it) {   // stage W: 32 f32/thread
            int idx = tid + it * 256;
            int wrow = idx >> 2, wseg = idx & 3;
            size_t base = (size_t)wrow * (IN_DIM / 4) + (k0 >> 2) + wseg * 4;
#pragma unroll
            for (int s = 0; s < 4; ++s) {
                float4 v = W4[base + s];
                int kk = wseg * 16 + s * 4;
                ushort h0 = f2bf(v.x), h1 = f2bf(v.y), h2 = f2bf(v.z), h3 = f2bf(v.w);
                ushort e0 = f2bf(v.x - bf2f(h0)), e1 = f2bf(v.y - bf2f(h1));
                ushort e2 = f2bf(v.z - bf2f(h2)), e3 = f2bf(v.w - bf2f(h3));
                uint2 ph; ph.x = pack2(h0, h1); ph.y = pack2(h2, h3);
                uint2 pl; pl.x = pack2(e0, e1); pl.y = pack2(e2, e3);
                *(uint2*)&wh[wrow][kk] = ph;
                *(uint2*)&wl[wrow][kk] = pl;
            }
        }
        __syncthreads();
#pragma unroll
        for (int ks = 0; ks < 4; ++ks) {
            int ko = ks * 16 + lg * 8;
            bf16x8 aH  = *(const bf16x8*)&xh[mrow + l31][ko];
            bf16x8 aL  = *(const bf16x8*)&xl[mrow + l31][ko];
            bf16x8 b0H = *(const bf16x8*)&wh[nbase + l31][ko];
            bf16x8 b0L = *(const bf16x8*)&wl[nbase + l31][ko];
            bf16x8 b1H = *(const bf16x8*)&wh[nbase + 32 + l31][ko];
            bf16x8 b1L = *(const bf16x8*)&wl[nbase + 32 + l31][ko];
            acc0 = __builtin_amdgcn_mfma_f32_32x32x16_bf16(aH, b0H, acc0, 0, 0, 0);
            acc0 = __builtin_amdgcn_mfma_f32_32x32x16_bf16(aH, b0L, acc0, 0, 0, 0);
            acc0 = __builtin_amdgcn_mfma_f32_32x32x16_bf16(aL, b0H, acc0, 0, 0, 0);
            acc1 = __builtin_amdgcn_mfma_f32_32x32x16_bf16(aH, b1H, acc1, 0, 0, 0);
            acc1 = __builtin_amdgcn_mfma_f32_32x32x16_bf16(aH, b1L, acc1, 0, 0, 0);
            acc1 = __builtin_amdgcn_mfma_f32_32x32x16_bf16(aL, b1H, acc1, 0, 0, 0);
        }
        __syncthreads();
    }

    // epilogue: write h + fused src/dst dots
    float asv0 = a_src[nbase + l31], asv1 = a_src[nbase + 32 + l31];
    float adv0 = a_dst[nbase + l31], adv1 = a_dst[nbase + 32 + l31];
#pragma unroll
    for (int r = 0; r < 16; ++r) {
        int row = (r & 3) + 8 * (r >> 2) + 4 * lg;
        size_t off = (size_t)(m0 + mrow + row) * OUT_DIM + nbase;
        h[off + l31] = acc0[r];
        h[off + 32 + l31] = acc1[r];
        float ps = acc0[r] * asv0 + acc1[r] * asv1;
        float pd = acc0[r] * adv0 + acc1[r] * adv1;
#pragma unroll
        for (int s = 1; s < 32; s <<= 1) {
            ps += __shfl_xor(ps, s, 32);
            pd += __shfl_xor(pd, s, 32);
        }
        if (l31 == 0) {
            redS[mrow + row][wv & 1] = ps;
            redD[mrow + row][wv & 1] = pd;
        }
    }
    __syncthreads();
    if (tid < 64) {
        src[m0 + tid]  = redS[tid][0] + redS[tid][1];
        dstv[m0 + tid] = redD[tid][0] + redD[tid][1];
    }
}

// ---------------- Kernel R: fused rank + scatter + weights (+bucket zero) ----------------
__global__ __launch_bounds__(256) void rank_kernel(
    const float* __restrict__ dstv, const int* __restrict__ mask,
    float* __restrict__ sorted_d, int* __restrict__ sorted_idx,
    float* __restrict__ wpos, float* __restrict__ wneg,
    int* __restrict__ bucketCnt)
{
    __shared__ float ld[8 * LDP];
    __shared__ int   red[32][8];
    const int tid = threadIdx.x;
    const int b  = blockIdx.x >> 6;
    const int jg = blockIdx.x & 63;
    if (tid == 0) bucketCnt[blockIdx.x] = 0;
    for (int i = tid; i < NN; i += 256)
        ld[(i >> 8) * LDP + (i & 255)] = dstv[b * NN + i];
    __syncthreads();
    const int js = tid >> 3;
    const int qq = tid & 7;
    const int jloc = jg * 32 + js;
    float myd = ld[(jloc >> 8) * LDP + (jloc & 255)];
    const float4* l4 = (const float4*)&ld[qq * LDP];
    int rank = 0;
#pragma unroll 8
    for (int t = 0; t < 64; ++t) {
        float4 v = l4[t];
        int jj = qq * 256 + t * 4;
        rank += (v.x < myd) || (v.x == myd && jj + 0 < jloc);
        rank += (v.y < myd) || (v.y == myd && jj + 1 < jloc);
        rank += (v.z < myd) || (v.z == myd && jj + 2 < jloc);
        rank += (v.w < myd) || (v.w == myd && jj + 3 < jloc);
    }
    red[js][qq] = rank;
    __syncthreads();
    if (tid < 32) {
        int j = jg * 32 + tid;
        const int* rr = red[tid];
        int rk = rr[0] + rr[1] + rr[2] + rr[3] + rr[4] + rr[5] + rr[6] + rr[7];
        float d = ld[(j >> 8) * LDP + (j & 255)];
        int mk = mask[b * NN + j];
        sorted_d[b * NN + rk] = d;
        sorted_idx[b * NN + rk] = j;
        wpos[b * NN + rk] = mk ? expf(d) : 0.f;
        wneg[b * NN + rk] = mk ? expf(0.2f * d) : 0.f;
    }
}

// ---------------- Kernel D1: chunk sums + query search/bucketing ----------------
__global__ __launch_bounds__(256) void chunksum_kernel(
    const float* __restrict__ h, const int* __restrict__ sidx,
    const float* __restrict__ wpos, const float* __restrict__ wneg,
    const float* __restrict__ sorted_d, const float* __restrict__ src,
    float* __restrict__ cPos, float* __restrict__ cNeg,
    float* __restrict__ cPosW, float* __restrict__ cNegW,
    int* __restrict__ lo_arr, int* __restrict__ bucketCnt, int* __restrict__ bucketList)
{
    __shared__ float sd_s[NN];     // 8 KB
    const int tid = threadIdx.x;
    const int b = blockIdx.x >> 6;
    const int c = blockIdx.x & 63;
    const int r0 = c * CHUNK;
    const float4* sd4 = (const float4*)(sorted_d + b * NN);
    {
        float4 v0 = sd4[tid];
        *(float4*)&sd_s[tid * 4] = v0;
        float4 v1 = sd4[256 + tid];
        *(float4*)&sd_s[1024 + tid * 4] = v1;
    }
    __syncthreads();
    if (tid < 128) {
        int o = tid;
        float ap = 0.f, an = 0.f, apw = 0.f, anw = 0.f;
#pragma unroll 8
        for (int r = 0; r < CHUNK; ++r) {
            int rr = b * NN + r0 + r;
            int jj = sidx[rr];
            float wp = wpos[rr], wn = wneg[rr];
            float hv = h[((size_t)b * NN + jj) * OUT_DIM + o];
            ap = fmaf(wp, hv, ap);
            an = fmaf(wn, hv, an);
            apw += wp; anw += wn;
        }
        int cidx = blockIdx.x;
        cPos[(size_t)cidx * OUT_DIM + o] = ap;
        cNeg[(size_t)cidx * OUT_DIM + o] = an;
        if (o == 0) { cPosW[cidx] = apw; cNegW[cidx] = anw; }
    } else if (tid < 160) {
        int ql = r0 + (tid - 128);
        int q = b * NN + ql;
        float t = -src[q];
        int lo = 0, hi = NN;
        while (lo < hi) {
            int mid = (lo + hi) >> 1;
            if (sd_s[mid] > t) hi = mid; else lo = mid + 1;
        }
        lo_arr[q] = lo;
        int cq = lo >> 5; if (cq > NCHUNK - 1) cq = NCHUNK - 1;
        int bidx = b * NCHUNK + cq;
        int pos = atomicAdd(&bucketCnt[bidx], 1);
        bucketList[(size_t)bidx * NN + pos] = q;
    }
}

// ---------------- Kernel E: fused expand + query (per split-chunk bucket) ----------------
__global__ __launch_bounds__(256, 2) void fusedout_kernel(
    const float* __restrict__ h, const int* __restrict__ sidx,
    const float* __restrict__ wpos, const float* __restrict__ wneg,
    const float* __restrict__ cPos, const float* __restrict__ cNeg,
    const float* __restrict__ cPosW, const float* __restrict__ cNegW,
    const float* __restrict__ src, const int* __restrict__ lo_arr,
    const int* __restrict__ bucketCnt, const int* __restrict__ bucketList,
    float* __restrict__ out)
{
    __shared__ float hs[CHUNK][OUT_DIM];
    __shared__ float PreL[CHUNK + 1][OUT_DIM];
    __shared__ float SufL[CHUNK + 1][OUT_DIM];
    __shared__ float wn_s[CHUNK], wp_s[CHUNK];
    __shared__ int   si_s[CHUNK];
    __shared__ float prewL[CHUNK + 1], sufwL[CHUNK + 1];
    __shared__ float prewBase, sufwBase;
    const int tid = threadIdx.x;
    const int b = blockIdx.x >> 6;
    const int c = blockIdx.x & 63;
    const int r0 = c * CHUNK;
    const size_t hb = (size_t)b * NN;

    if (tid < CHUNK) {
        int rr = b * NN + r0 + tid;
        si_s[tid] = sidx[rr];
        wn_s[tid] = wneg[rr];
        wp_s[tid] = wpos[rr];
    }
    __syncthreads();
#pragma unroll
    for (int it = 0; it < 4; ++it) {
        int row = it * 8 + (tid >> 5);
        int c4 = tid & 31;
        float4 v = ((const float4*)h)[(hb + si_s[row]) * (OUT_DIM / 4) + c4];
        *(float4*)&hs[row][c4 * 4] = v;
    }
    // scalar weight bases: 64-lane parallel load + shfl reduce (waves 2 & 3)
    {
        int wvid = tid >> 6;
        if (wvid == 2) {
            int l = tid & 63;
            float v = (l < c) ? cNegW[b * NCHUNK + l] : 0.f;
#pragma unroll
            for (int s = 1; s < 64; s <<= 1) v += __shfl_xor(v, s);
            if (l == 0) prewBase = v;
        } else if (wvid == 3) {
            int l = tid & 63;
            float v = (l > c) ? cPosW[b * NCHUNK + l] : 0.f;
#pragma unroll
            for (int s = 1; s < 64; s <<= 1) v += __shfl_xor(v, s);
            if (l == 0) sufwBase = v;
        }
    }
    // vector bases: 4-way unrolled accumulators (4 loads in flight)
    float base;
    if (tid < 128) {
        const float* p = cNeg + (size_t)(b * NCHUNK) * OUT_DIM + tid;
        float b0 = 0.f, b1 = 0.f, b2 = 0.f, b3 = 0.f;
        int cc = 0;
        for (; cc + 4 <= c; cc += 4) {
            b0 += p[(size_t)(cc + 0) * OUT_DIM];
            b1 += p[(size_t)(cc + 1) * OUT_DIM];
            b2 += p[(size_t)(cc + 2) * OUT_DIM];
            b3 += p[(size_t)(cc + 3) * OUT_DIM];
        }
        for (; cc < c; ++cc) b0 += p[(size_t)cc * OUT_DIM];
        base = (b0 + b1) + (b2 + b3);
    } else {
        const float* p = cPos + (size_t)(b * NCHUNK) * OUT_DIM + (tid - 128);
        float b0 = 0.f, b1 = 0.f, b2 = 0.f, b3 = 0.f;
        int cc = c + 1;
        for (; cc + 4 <= NCHUNK; cc += 4) {
            b0 += p[(size_t)(cc + 0) * OUT_DIM];
            b1 += p[(size_t)(cc + 1) * OUT_DIM];
            b2 += p[(size_t)(cc + 2) * OUT_DIM];
            b3 += p[(size_t)(cc + 3) * OUT_DIM];
        }
        for (; cc < NCHUNK; ++cc) b0 += p[(size_t)cc * OUT_DIM];
        base = (b0 + b1) + (b2 + b3);
    }
    __syncthreads();
    if (tid < 128) {
        int o = tid;
        float acc = base;
#pragma unroll
        for (int r = 0; r < CHUNK; ++r) {
            PreL[r][o] = acc;
            acc = fmaf(wn_s[r], hs[r][o], acc);
        }
        PreL[CHUNK][o] = acc;
    } else {
        int o = tid - 128;
        float acc = base;
        SufL[CHUNK][o] = acc;
#pragma unroll
        for (int r = CHUNK - 1; r >= 0; --r) {
            acc = fmaf(wp_s[r], hs[r][o], acc);
            SufL[r][o] = acc;
        }
    }
    if (tid == 0) {
        float a = prewBase;
        for (int r = 0; r < CHUNK; ++r) { prewL[r] = a; a += wn_s[r]; }
        prewL[CHUNK] = a;
    }
    if (tid == 128) {
        float a = sufwBase;
        sufwL[CHUNK] = a;
        for (int r = CHUNK - 1; r >= 0; --r) { a += wp_s[r]; sufwL[r] = a; }
    }
    __syncthreads();

    const int bidx = blockIdx.x;
    const int cnt = bucketCnt[bidx];
    const int o  = tid & 127;
    const int qh = tid >> 7;
    for (int i = qh; i < cnt; i += 2) {
        int q = bucketList[(size_t)bidx * NN + i];
        int rl = lo_arr[q] - r0;               // 0..32
        float sv = src[q];
        float pe = expf(sv), pn = expf(0.2f * sv);
        float den = pe * sufwL[rl] + pn * prewL[rl];
        float sc = (den > 0.f) ? 1.f / den : 0.f;
        float num = pe * SufL[rl][o] + pn * PreL[rl][o];
        out[(size_t)q * OUT_DIM + o] = num * sc;
    }
}

// ---------------- launcher ----------------
extern "C" void kernel_launch(void* const* d_in, const int* in_sizes, int n_in,
                              void* d_out, int out_size, void* d_ws, size_t ws_size,
                              hipStream_t stream)
{
    const float* x     = (const float*)d_in[0];
    const int*   mask  = (const int*)d_in[1];
    const float* W     = (const float*)d_in[2];
    const float* a_src = (const float*)d_in[3];
    const float* a_dst = (const float*)d_in[4];
    float* out = (float*)d_out;
    float* ws  = (float*)d_ws;

    float* h        = ws + OFF_H;
    float* src      = ws + OFF_SRC;
    float* dstv     = ws + OFF_DST;
    float* sorted_d = ws + OFF_SD;
    int*   sidx     = (int*)(ws + OFF_SI);
    float* wpos     = ws + OFF_WP;
    float* wneg     = ws + OFF_WN;
    float* cPos     = ws + OFF_CP;
    float* cNeg     = ws + OFF_CN;
    float* cPosW    = ws + OFF_CPW;
    float* cNegW    = ws + OFF_CNW;
    int*   lo_arr   = (int*)(ws + OFF_LO);
    int*   bucketCnt= (int*)(ws + OFF_BCNT);
    int*   bucketList=(int*)(ws + OFF_BLST);

    gat_gemm_kernel<<<M_TOT / 64, 256, 0, stream>>>(x, W, a_src, a_dst, h, src, dstv);
    rank_kernel<<<NBUCKET, 256, 0, stream>>>(dstv, mask, sorted_d, sidx, wpos, wneg, bucketCnt);
    chunksum_kernel<<<NBUCKET, 256, 0, stream>>>(h, sidx, wpos, wneg, sorted_d, src,
                                                 cPos, cNeg, cPosW, cNegW,
                                                 lo_arr, bucketCnt, bucketList);
    fusedout_kernel<<<NBUCKET, 256, 0, stream>>>(h, sidx, wpos, wneg, cPos, cNeg, cPosW, cNegW,
                                                 src, lo_arr, bucketCnt, bucketList, out);
}

// Round 16
// 54.920 us; speedup vs baseline: 3.0209x; 1.0131x over previous
//
#include <hip/hip_runtime.h>
#include <math.h>

#define BB 8
#define NN 2048
#define IN_DIM 256
#define OUT_DIM 128
#define M_TOT (BB*NN)          // 16384
#define CHUNK 32
#define NCHUNK (NN/CHUNK)      // 64
#define LDP 264                // padded rank-chunk stride (floats)
#define NBUCKET (BB*NCHUNK)    // 512

typedef __attribute__((ext_vector_type(8))) short bf16x8;
typedef __attribute__((ext_vector_type(16))) float f32x16;

__device__ inline ushort f2bf(float f) {
    unsigned u = __float_as_uint(f);
    unsigned r = (u + 0x7FFFu + ((u >> 16) & 1u)) >> 16;   // RNE
    return (ushort)r;
}
__device__ inline float bf2f(ushort b) { return __uint_as_float(((unsigned)b) << 16); }
__device__ inline unsigned pack2(ushort a, ushort b) { return (unsigned)a | ((unsigned)b << 16); }

// ---------------- workspace layout (in floats) ----------------
static const size_t OFF_H    = 0;                                   // h: M_TOT*128
static const size_t OFF_SRC  = OFF_H   + (size_t)M_TOT*OUT_DIM;
static const size_t OFF_DST  = OFF_SRC + M_TOT;
static const size_t OFF_SD   = OFF_DST + M_TOT;                     // sorted_d
static const size_t OFF_SI   = OFF_SD  + M_TOT;                     // sorted_idx (int)
static const size_t OFF_WP   = OFF_SI  + M_TOT;                     // wpos (sorted order)
static const size_t OFF_WN   = OFF_WP  + M_TOT;                     // wneg
static const size_t OFF_CP   = OFF_WN  + M_TOT;                     // chunk sums
static const size_t OFF_CN   = OFF_CP  + (size_t)NBUCKET*OUT_DIM;
static const size_t OFF_CPW  = OFF_CN  + (size_t)NBUCKET*OUT_DIM;
static const size_t OFF_CNW  = OFF_CPW + NBUCKET;
static const size_t OFF_LO   = OFF_CNW + NBUCKET;                   // lo per query (int)
static const size_t OFF_BCNT = OFF_LO  + M_TOT;                     // bucket counts (int)
static const size_t OFF_BLST = OFF_BCNT + NBUCKET;                  // bucket lists (int)

// ---------------- Kernel A: MFMA bf16x2-split GEMM + src/dst dots ----------------
// Register-prefetch pipeline: K-tile t+1's global loads issue before tile t's
// MFMA phase; convert+LDS-write after the post-MFMA barrier. Load latency
// hides under MFMA instead of draining at the barrier.
__global__ __launch_bounds__(256) void gat_gemm_kernel(
    const float* __restrict__ x, const float* __restrict__ W,
    const float* __restrict__ a_src, const float* __restrict__ a_dst,
    float* __restrict__ h, float* __restrict__ src, float* __restrict__ dstv)
{
    __shared__ ushort xh[64][72], xl[64][72];     // 9216 B each
    __shared__ ushort wh[128][72], wl[128][72];   // 18432 B each
    __shared__ float  redS[64][2], redD[64][2];
    const int tid  = threadIdx.x;
    const int lane = tid & 63;
    const int wv   = tid >> 6;            // 0..3
    const int m0   = blockIdx.x * 64;
    const int mrow = (wv >> 1) * 32;      // 0 / 32
    const int nbase = (wv & 1) * 64;      // 0 / 64
    const int l31  = lane & 31;
    const int lg   = lane >> 5;           // k-chunk group 0/1

    f32x16 acc0, acc1;
#pragma unroll
    for (int i = 0; i < 16; ++i) { acc0[i] = 0.f; acc1[i] = 0.f; }

    const float4* x4 = (const float4*)x;
    const float4* W4 = (const float4*)W;
    const int xrow = tid >> 2, xseg = tid & 3;   // x: 64 rows x 4 segs of 16
    const int wrow0 = tid >> 2, wrow1 = (tid + 256) >> 2, wseg = tid & 3;

    float4 xstg[4], wstg[2][4];

#define LOADT(k0)                                                              \
    {                                                                          \
        size_t xb = (size_t)(m0 + xrow) * (IN_DIM / 4) + ((k0) >> 2) + xseg * 4; \
        _Pragma("unroll")                                                      \
        for (int s = 0; s < 4; ++s) xstg[s] = x4[xb + s];                      \
        size_t wb0 = (size_t)wrow0 * (IN_DIM / 4) + ((k0) >> 2) + wseg * 4;    \
        size_t wb1 = (size_t)wrow1 * (IN_DIM / 4) + ((k0) >> 2) + wseg * 4;    \
        _Pragma("unroll")                                                      \
        for (int s = 0; s < 4; ++s) { wstg[0][s] = W4[wb0 + s]; wstg[1][s] = W4[wb1 + s]; } \
    }
#define CVTW(v, dsth, dstl, row, kk)                                           \
    {                                                                          \
        ushort h0 = f2bf((v).x), h1 = f2bf((v).y), h2 = f2bf((v).z), h3 = f2bf((v).w); \
        ushort e0 = f2bf((v).x - bf2f(h0)), e1 = f2bf((v).y - bf2f(h1));       \
        ushort e2 = f2bf((v).z - bf2f(h2)), e3 = f2bf((v).w - bf2f(h3));       \
        uint2 ph; ph.x = pack2(h0, h1); ph.y = pack2(h2, h3);                  \
        uint2 pl; pl.x = pack2(e0, e1); pl.y = pack2(e2, e3);                  \
        *(uint2*)&dsth[row][kk] = ph;                                          \
        *(uint2*)&dstl[row][kk] = pl;                                          \
    }
#define WRITET()                                                               \
    {                                                                          \
        _Pragma("unroll")                                                      \
        for (int s = 0; s < 4; ++s) CVTW(xstg[s], xh, xl, xrow, xseg * 16 + s * 4); \
        _Pragma("unroll")                                                      \
        for (int s = 0; s < 4; ++s) CVTW(wstg[0][s], wh, wl, wrow0, wseg * 16 + s * 4); \
        _Pragma("unroll")                                                      \
        for (int s = 0; s < 4; ++s) CVTW(wstg[1][s], wh, wl, wrow1, wseg * 16 + s * 4); \
    }

    LOADT(0);
    WRITET();
    __syncthreads();

    for (int kt = 0; kt < 4; ++kt) {
        if (kt < 3) LOADT((kt + 1) * 64);     // prefetch next tile into regs
#pragma unroll
        for (int ks = 0; ks < 4; ++ks) {
            int ko = ks * 16 + lg * 8;
            bf16x8 aH  = *(const bf16x8*)&xh[mrow + l31][ko];
            bf16x8 aL  = *(const bf16x8*)&xl[mrow + l31][ko];
            bf16x8 b0H = *(const bf16x8*)&wh[nbase + l31][ko];
            bf16x8 b0L = *(const bf16x8*)&wl[nbase + l31][ko];
            bf16x8 b1H = *(const bf16x8*)&wh[nbase + 32 + l31][ko];
            bf16x8 b1L = *(const bf16x8*)&wl[nbase + 32 + l31][ko];
            acc0 = __builtin_amdgcn_mfma_f32_32x32x16_bf16(aH, b0H, acc0, 0, 0, 0);
            acc0 = __builtin_amdgcn_mfma_f32_32x32x16_bf16(aH, b0L, acc0, 0, 0, 0);
            acc0 = __builtin_amdgcn_mfma_f32_32x32x16_bf16(aL, b0H, acc0, 0, 0, 0);
            acc1 = __builtin_amdgcn_mfma_f32_32x32x16_bf16(aH, b1H, acc1, 0, 0, 0);
            acc1 = __builtin_amdgcn_mfma_f32_32x32x16_bf16(aH, b1L, acc1, 0, 0, 0);
            acc1 = __builtin_amdgcn_mfma_f32_32x32x16_bf16(aL, b1H, acc1, 0, 0, 0);
        }
        __syncthreads();                       // all waves done reading LDS
        if (kt < 3) {
            WRITET();                          // convert + write next tile
            __syncthreads();
        }
    }

    // epilogue: write h + fused src/dst dots
    float asv0 = a_src[nbase + l31], asv1 = a_src[nbase + 32 + l31];
    float adv0 = a_dst[nbase + l31], adv1 = a_dst[nbase + 32 + l31];
#pragma unroll
    for (int r = 0; r < 16; ++r) {
        int row = (r & 3) + 8 * (r >> 2) + 4 * lg;
        size_t off = (size_t)(m0 + mrow + row) * OUT_DIM + nbase;
        h[off + l31] = acc0[r];
        h[off + 32 + l31] = acc1[r];
        float ps = acc0[r] * asv0 + acc1[r] * asv1;
        float pd = acc0[r] * adv0 + acc1[r] * adv1;
#pragma unroll
        for (int s = 1; s < 32; s <<= 1) {
            ps += __shfl_xor(ps, s, 32);
            pd += __shfl_xor(pd, s, 32);
        }
        if (l31 == 0) {
            redS[mrow + row][wv & 1] = ps;
            redD[mrow + row][wv & 1] = pd;
        }
    }
    __syncthreads();
    if (tid < 64) {
        src[m0 + tid]  = redS[tid][0] + redS[tid][1];
        dstv[m0 + tid] = redD[tid][0] + redD[tid][1];
    }
}

// ---------------- Kernel R: fused rank + scatter + weights (+bucket zero) ----------------
__global__ __launch_bounds__(256) void rank_kernel(
    const float* __restrict__ dstv, const int* __restrict__ mask,
    float* __restrict__ sorted_d, int* __restrict__ sorted_idx,
    float* __restrict__ wpos, float* __restrict__ wneg,
    int* __restrict__ bucketCnt)
{
    __shared__ float ld[8 * LDP];
    __shared__ int   red[32][8];
    const int tid = threadIdx.x;
    const int b  = blockIdx.x >> 6;
    const int jg = blockIdx.x & 63;
    if (tid == 0) bucketCnt[blockIdx.x] = 0;
    for (int i = tid; i < NN; i += 256)
        ld[(i >> 8) * LDP + (i & 255)] = dstv[b * NN + i];
    __syncthreads();
    const int js = tid >> 3;
    const int qq = tid & 7;
    const int jloc = jg * 32 + js;
    float myd = ld[(jloc >> 8) * LDP + (jloc & 255)];
    const float4* l4 = (const float4*)&ld[qq * LDP];
    int rank = 0;
#pragma unroll 8
    for (int t = 0; t < 64; ++t) {
        float4 v = l4[t];
        int jj = qq * 256 + t * 4;
        rank += (v.x < myd) || (v.x == myd && jj + 0 < jloc);
        rank += (v.y < myd) || (v.y == myd && jj + 1 < jloc);
        rank += (v.z < myd) || (v.z == myd && jj + 2 < jloc);
        rank += (v.w < myd) || (v.w == myd && jj + 3 < jloc);
    }
    red[js][qq] = rank;
    __syncthreads();
    if (tid < 32) {
        int j = jg * 32 + tid;
        const int* rr = red[tid];
        int rk = rr[0] + rr[1] + rr[2] + rr[3] + rr[4] + rr[5] + rr[6] + rr[7];
        float d = ld[(j >> 8) * LDP + (j & 255)];
        int mk = mask[b * NN + j];
        sorted_d[b * NN + rk] = d;
        sorted_idx[b * NN + rk] = j;
        wpos[b * NN + rk] = mk ? expf(d) : 0.f;
        wneg[b * NN + rk] = mk ? expf(0.2f * d) : 0.f;
    }
}

// ---------------- Kernel D1: chunk sums + query search/bucketing ----------------
__global__ __launch_bounds__(256) void chunksum_kernel(
    const float* __restrict__ h, const int* __restrict__ sidx,
    const float* __restrict__ wpos, const float* __restrict__ wneg,
    const float* __restrict__ sorted_d, const float* __restrict__ src,
    float* __restrict__ cPos, float* __restrict__ cNeg,
    float* __restrict__ cPosW, float* __restrict__ cNegW,
    int* __restrict__ lo_arr, int* __restrict__ bucketCnt, int* __restrict__ bucketList)
{
    __shared__ float sd_s[NN];     // 8 KB
    const int tid = threadIdx.x;
    const int b = blockIdx.x >> 6;
    const int c = blockIdx.x & 63;
    const int r0 = c * CHUNK;
    const float4* sd4 = (const float4*)(sorted_d + b * NN);
    {
        float4 v0 = sd4[tid];
        *(float4*)&sd_s[tid * 4] = v0;
        float4 v1 = sd4[256 + tid];
        *(float4*)&sd_s[1024 + tid * 4] = v1;
    }
    __syncthreads();
    if (tid < 128) {
        int o = tid;
        float ap = 0.f, an = 0.f, apw = 0.f, anw = 0.f;
#pragma unroll 8
        for (int r = 0; r < CHUNK; ++r) {
            int rr = b * NN + r0 + r;
            int jj = sidx[rr];
            float wp = wpos[rr], wn = wneg[rr];
            float hv = h[((size_t)b * NN + jj) * OUT_DIM + o];
            ap = fmaf(wp, hv, ap);
            an = fmaf(wn, hv, an);
            apw += wp; anw += wn;
        }
        int cidx = blockIdx.x;
        cPos[(size_t)cidx * OUT_DIM + o] = ap;
        cNeg[(size_t)cidx * OUT_DIM + o] = an;
        if (o == 0) { cPosW[cidx] = apw; cNegW[cidx] = anw; }
    } else if (tid < 160) {
        int ql = r0 + (tid - 128);
        int q = b * NN + ql;
        float t = -src[q];
        int lo = 0, hi = NN;
        while (lo < hi) {
            int mid = (lo + hi) >> 1;
            if (sd_s[mid] > t) hi = mid; else lo = mid + 1;
        }
        lo_arr[q] = lo;
        int cq = lo >> 5; if (cq > NCHUNK - 1) cq = NCHUNK - 1;
        int bidx = b * NCHUNK + cq;
        int pos = atomicAdd(&bucketCnt[bidx], 1);
        bucketList[(size_t)bidx * NN + pos] = q;
    }
}

// ---------------- Kernel E: fused expand + query (per split-chunk bucket) ----------------
__global__ __launch_bounds__(256, 2) void fusedout_kernel(
    const float* __restrict__ h, const int* __restrict__ sidx,
    const float* __restrict__ wpos, const float* __restrict__ wneg,
    const float* __restrict__ cPos, const float* __restrict__ cNeg,
    const float* __restrict__ cPosW, const float* __restrict__ cNegW,
    const float* __restrict__ src, const int* __restrict__ lo_arr,
    const int* __restrict__ bucketCnt, const int* __restrict__ bucketList,
    float* __restrict__ out)
{
    __shared__ float hs[CHUNK][OUT_DIM];
    __shared__ float PreL[CHUNK + 1][OUT_DIM];
    __shared__ float SufL[CHUNK + 1][OUT_DIM];
    __shared__ float wn_s[CHUNK], wp_s[CHUNK];
    __shared__ int   si_s[CHUNK];
    __shared__ float prewL[CHUNK + 1], sufwL[CHUNK + 1];
    __shared__ float prewBase, sufwBase;
    const int tid = threadIdx.x;
    const int b = blockIdx.x >> 6;
    const int c = blockIdx.x & 63;
    const int r0 = c * CHUNK;
    const size_t hb = (size_t)b * NN;

    if (tid < CHUNK) {
        int rr = b * NN + r0 + tid;
        si_s[tid] = sidx[rr];
        wn_s[tid] = wneg[rr];
        wp_s[tid] = wpos[rr];
    }
    __syncthreads();
#pragma unroll
    for (int it = 0; it < 4; ++it) {
        int row = it * 8 + (tid >> 5);
        int c4 = tid & 31;
        float4 v = ((const float4*)h)[(hb + si_s[row]) * (OUT_DIM / 4) + c4];
        *(float4*)&hs[row][c4 * 4] = v;
    }
    // scalar weight bases: 64-lane parallel load + shfl reduce (waves 2 & 3)
    {
        int wvid = tid >> 6;
        if (wvid == 2) {
            int l = tid & 63;
            float v = (l < c) ? cNegW[b * NCHUNK + l] : 0.f;
#pragma unroll
            for (int s = 1; s < 64; s <<= 1) v += __shfl_xor(v, s);
            if (l == 0) prewBase = v;
        } else if (wvid == 3) {
            int l = tid & 63;
            float v = (l > c) ? cPosW[b * NCHUNK + l] : 0.f;
#pragma unroll
            for (int s = 1; s < 64; s <<= 1) v += __shfl_xor(v, s);
            if (l == 0) sufwBase = v;
        }
    }
    // vector bases: 8-way unrolled accumulators (8 loads in flight)
    float base;
    if (tid < 128) {
        const float* p = cNeg + (size_t)(b * NCHUNK) * OUT_DIM + tid;
        float b0 = 0.f, b1 = 0.f, b2 = 0.f, b3 = 0.f;
        float b4 = 0.f, b5 = 0.f, b6 = 0.f, b7 = 0.f;
        int cc = 0;
        for (; cc + 8 <= c; cc += 8) {
            b0 += p[(size_t)(cc + 0) * OUT_DIM];
            b1 += p[(size_t)(cc + 1) * OUT_DIM];
            b2 += p[(size_t)(cc + 2) * OUT_DIM];
            b3 += p[(size_t)(cc + 3) * OUT_DIM];
            b4 += p[(size_t)(cc + 4) * OUT_DIM];
            b5 += p[(size_t)(cc + 5) * OUT_DIM];
            b6 += p[(size_t)(cc + 6) * OUT_DIM];
            b7 += p[(size_t)(cc + 7) * OUT_DIM];
        }
        for (; cc < c; ++cc) b0 += p[(size_t)cc * OUT_DIM];
        base = ((b0 + b1) + (b2 + b3)) + ((b4 + b5) + (b6 + b7));
    } else {
        const float* p = cPos + (size_t)(b * NCHUNK) * OUT_DIM + (tid - 128);
        float b0 = 0.f, b1 = 0.f, b2 = 0.f, b3 = 0.f;
        float b4 = 0.f, b5 = 0.f, b6 = 0.f, b7 = 0.f;
        int cc = c + 1;
        for (; cc + 8 <= NCHUNK; cc += 8) {
            b0 += p[(size_t)(cc + 0) * OUT_DIM];
            b1 += p[(size_t)(cc + 1) * OUT_DIM];
            b2 += p[(size_t)(cc + 2) * OUT_DIM];
            b3 += p[(size_t)(cc + 3) * OUT_DIM];
            b4 += p[(size_t)(cc + 4) * OUT_DIM];
            b5 += p[(size_t)(cc + 5) * OUT_DIM];
            b6 += p[(size_t)(cc + 6) * OUT_DIM];
            b7 += p[(size_t)(cc + 7) * OUT_DIM];
        }
        for (; cc < NCHUNK; ++cc) b0 += p[(size_t)cc * OUT_DIM];
        base = ((b0 + b1) + (b2 + b3)) + ((b4 + b5) + (b6 + b7));
    }
    __syncthreads();
    if (tid < 128) {
        int o = tid;
        float acc = base;
#pragma unroll
        for (int r = 0; r < CHUNK; ++r) {
            PreL[r][o] = acc;
            acc = fmaf(wn_s[r], hs[r][o], acc);
        }
        PreL[CHUNK][o] = acc;
    } else {
        int o = tid - 128;
        float acc = base;
        SufL[CHUNK][o] = acc;
#pragma unroll
        for (int r = CHUNK - 1; r >= 0; --r) {
            acc = fmaf(wp_s[r], hs[r][o], acc);
            SufL[r][o] = acc;
        }
    }
    if (tid == 0) {
        float a = prewBase;
        for (int r = 0; r < CHUNK; ++r) { prewL[r] = a; a += wn_s[r]; }
        prewL[CHUNK] = a;
    }
    if (tid == 128) {
        float a = sufwBase;
        sufwL[CHUNK] = a;
        for (int r = CHUNK - 1; r >= 0; --r) { a += wp_s[r]; sufwL[r] = a; }
    }
    __syncthreads();

    const int bidx = blockIdx.x;
    const int cnt = bucketCnt[bidx];
    const int o  = tid & 127;
    const int qh = tid >> 7;
    for (int i = qh; i < cnt; i += 2) {
        int q = bucketList[(size_t)bidx * NN + i];
        int rl = lo_arr[q] - r0;               // 0..32
        float sv = src[q];
        float pe = expf(sv), pn = expf(0.2f * sv);
        float den = pe * sufwL[rl] + pn * prewL[rl];
        float sc = (den > 0.f) ? 1.f / den : 0.f;
        float num = pe * SufL[rl][o] + pn * PreL[rl][o];
        out[(size_t)q * OUT_DIM + o] = num * sc;
    }
}

// ---------------- launcher ----------------
extern "C" void kernel_launch(void* const* d_in, const int* in_sizes, int n_in,
                              void* d_out, int out_size, void* d_ws, size_t ws_size,
                              hipStream_t stream)
{
    const float* x     = (const float*)d_in[0];
    const int*   mask  = (const int*)d_in[1];
    const float* W     = (const float*)d_in[2];
    const float* a_src = (const float*)d_in[3];
    const float* a_dst = (const float*)d_in[4];
    float* out = (float*)d_out;
    float* ws  = (float*)d_ws;

    float* h        = ws + OFF_H;
    float* src      = ws + OFF_SRC;
    float* dstv     = ws + OFF_DST;
    float* sorted_d = ws + OFF_SD;
    int*   sidx     = (int*)(ws + OFF_SI);
    float* wpos     = ws + OFF_WP;
    float* wneg     = ws + OFF_WN;
    float* cPos     = ws + OFF_CP;
    float* cNeg     = ws + OFF_CN;
    float* cPosW    = ws + OFF_CPW;
    float* cNegW    = ws + OFF_CNW;
    int*   lo_arr   = (int*)(ws + OFF_LO);
    int*   bucketCnt= (int*)(ws + OFF_BCNT);
    int*   bucketList=(int*)(ws + OFF_BLST);

    gat_gemm_kernel<<<M_TOT / 64, 256, 0, stream>>>(x, W, a_src, a_dst, h, src, dstv);
    rank_kernel<<<NBUCKET, 256, 0, stream>>>(dstv, mask, sorted_d, sidx, wpos, wneg, bucketCnt);
    chunksum_kernel<<<NBUCKET, 256, 0, stream>>>(h, sidx, wpos, wneg, sorted_d, src,
                                                 cPos, cNeg, cPosW, cNegW,
                                                 lo_arr, bucketCnt, bucketList);
    fusedout_kernel<<<NBUCKET, 256, 0, stream>>>(h, sidx, wpos, wneg, cPos, cNeg, cPosW, cNegW,
                                                 src, lo_arr, bucketCnt, bucketList, out);
}